// Round 1
// baseline (275.963 us; speedup 1.0000x reference)
//
#include <hip/hip_runtime.h>

#define IN_DIM 32
#define OUT_DIM 64

// Kernel 1: edge-parallel scatter-add.
// One thread per (edge, dim): 32 consecutive lanes handle the 32 dims of one
// edge -> feature reads are coalesced 128B segments; src/dst loads are
// broadcast across the 32 lanes (same address). atomicAdd resolves at L2.
__global__ __launch_bounds__(256) void mpnn_scatter_kernel(
    const float* __restrict__ feature,
    const int* __restrict__ src,
    const int* __restrict__ dst,
    float* __restrict__ h,
    int n_edges) {
    long long tid = (long long)blockIdx.x * blockDim.x + threadIdx.x;
    long long total = (long long)n_edges * IN_DIM;
    if (tid >= total) return;
    int e = (int)(tid >> 5);
    int d = (int)(tid & 31);
    int s = src[e];
    int t = dst[e];
    float v = feature[(long long)s * IN_DIM + d];
    atomicAdd(&h[(long long)t * IN_DIM + d], v);
}

// Kernel 2: out[row][col] = sum_k h[row][k] * W[k][col] + b[col]
// Block = 256 threads = 4 rows x 64 cols. W staged in LDS (8 KB), h rows in
// LDS. W LDS reads: 64 lanes hit consecutive cols -> 2 lanes/bank (free).
__global__ __launch_bounds__(256) void mpnn_proj_kernel(
    const float* __restrict__ h,
    const float* __restrict__ W,
    const float* __restrict__ b,
    float* __restrict__ out,
    int n_nodes) {
    __shared__ float Ws[IN_DIM * OUT_DIM];
    __shared__ float hs[4][IN_DIM];
    int tx = threadIdx.x;

    for (int i = tx; i < IN_DIM * OUT_DIM; i += 256) Ws[i] = W[i];

    int row0 = blockIdx.x * 4;
    if (tx < 4 * IN_DIM) {
        int r = tx >> 5, k = tx & 31;
        int row = row0 + r;
        hs[r][k] = (row < n_nodes) ? h[(long long)row * IN_DIM + k] : 0.0f;
    }
    __syncthreads();

    int col = tx & 63;
    int r = tx >> 6;
    int row = row0 + r;
    if (row >= n_nodes) return;

    float acc = b[col];
#pragma unroll
    for (int k = 0; k < IN_DIM; ++k)
        acc += hs[r][k] * Ws[k * OUT_DIM + col];

    out[(long long)row * OUT_DIM + col] = acc;
}

extern "C" void kernel_launch(void* const* d_in, const int* in_sizes, int n_in,
                              void* d_out, int out_size, void* d_ws, size_t ws_size,
                              hipStream_t stream) {
    const float* feature = (const float*)d_in[0];
    const int* src = (const int*)d_in[1];
    const int* dst = (const int*)d_in[2];
    const float* W = (const float*)d_in[3];
    const float* b = (const float*)d_in[4];
    float* out = (float*)d_out;

    int n_nodes = in_sizes[0] / IN_DIM;  // 100000
    int n_edges = in_sizes[1];           // 1600000

    float* h = (float*)d_ws;  // [n_nodes, IN_DIM] accumulator, 12.8 MB

    // Workspace is re-poisoned to 0xAA before every launch — zero it.
    hipMemsetAsync(h, 0, (size_t)n_nodes * IN_DIM * sizeof(float), stream);

    long long total = (long long)n_edges * IN_DIM;
    int threads = 256;
    int blocks = (int)((total + threads - 1) / threads);
    mpnn_scatter_kernel<<<blocks, threads, 0, stream>>>(feature, src, dst, h, n_edges);

    int pblocks = (n_nodes + 3) / 4;
    mpnn_proj_kernel<<<pblocks, 256, 0, stream>>>(h, W, b, out, n_nodes);
}